// Round 5
// baseline (803.292 us; speedup 1.0000x reference)
//
#include <hip/hip_runtime.h>
#include <hip/hip_bf16.h>

typedef unsigned short u16;
typedef __bf16 bf16x8 __attribute__((ext_vector_type(8)));
typedef float f32x4 __attribute__((ext_vector_type(4)));

#define DEV static __device__ __forceinline__

DEV u16 f2bf(float v) { __bf16 h = (__bf16)v; return __builtin_bit_cast(u16, h); }
DEV float bf2f(u16 u) { return (float)__builtin_bit_cast(__bf16, u); }

DEV void async16(const u16* g, u16* lds) {
  __builtin_amdgcn_global_load_lds(
      (const __attribute__((address_space(1))) unsigned int*)g,
      (__attribute__((address_space(3))) unsigned int*)lds, 16, 0, 0);
}

// ---------------- GEMM (bf16 MFMA): C = A[M,K] @ Bt[N,K]^T, 128x128 tile -----
// EPI: 0 = plain, 1 = +bias+relu, 2 = +bias+resid.  bias f32, rest bf16.
template <int EPI>
__global__ __launch_bounds__(256, 2) void gemm_bt(
    const u16* __restrict__ A, const u16* __restrict__ Bt, u16* __restrict__ C,
    int M, int N, int K,
    const float* __restrict__ bias, const u16* __restrict__ resid) {
  __shared__ u16 As[128 * 32];
  __shared__ u16 Bs[128 * 32];
  const int t = threadIdx.x;
  const int lane = t & 63;
  const int w = t >> 6, wr = w >> 1, wc = w & 1;
  const long bm = (long)blockIdx.y * 128, bn = (long)blockIdx.x * 128;

  f32x4 acc[4][4] = {};

  const int r_ld = t >> 2;
  const int k_ld = (t & 3) * 8;
  const u16* Ag = A + (bm + r_ld) * (long)K + k_ld;
  const u16* Bg = Bt + (bn + r_ld) * (long)K + k_ld;
  u16* As0 = &As[t * 8];
  u16* Bs0 = &Bs[t * 8];
  const long skip = 64 * (long)K;

  for (int k0 = 0; k0 < K; k0 += 32) {
    __syncthreads();
    async16(Ag + k0, As0);
    async16(Ag + k0 + skip, As0 + 2048);
    async16(Bg + k0, Bs0);
    async16(Bg + k0 + skip, Bs0 + 2048);
    __syncthreads();
    bf16x8 af[4], bfr[4];
#pragma unroll
    for (int m = 0; m < 4; ++m)
      af[m] = *(const bf16x8*)&As[(wr * 64 + m * 16 + (lane & 15)) * 32 + (lane >> 4) * 8];
#pragma unroll
    for (int n = 0; n < 4; ++n)
      bfr[n] = *(const bf16x8*)&Bs[(wc * 64 + n * 16 + (lane & 15)) * 32 + (lane >> 4) * 8];
#pragma unroll
    for (int m = 0; m < 4; ++m)
#pragma unroll
      for (int n = 0; n < 4; ++n)
        acc[m][n] = __builtin_amdgcn_mfma_f32_16x16x32_bf16(af[m], bfr[n], acc[m][n], 0, 0, 0);
  }

  const int r0 = wr * 64 + (lane >> 4) * 4;
  const int c0 = wc * 64 + (lane & 15);
#pragma unroll
  for (int m = 0; m < 4; ++m) {
#pragma unroll
    for (int n = 0; n < 4; ++n) {
      const long col = bn + c0 + n * 16;
      float bv = 0.f;
      if (EPI >= 1) bv = bias[col];
#pragma unroll
      for (int r = 0; r < 4; ++r) {
        const long row = bm + r0 + m * 16 + r;
        float v = acc[m][n][r] + bv;
        if (EPI == 1) v = fmaxf(v, 0.f);
        if (EPI == 2) v += bf2f(resid[row * (long)N + col]);
        C[row * (long)N + col] = f2bf(v);
      }
    }
  }
}

// ---------------- f32 VALU GEMM: {Q,K} = A[M,1024] @ W[1024,1024] ------------
// grid (N/128, M/128, 2); z=0 -> (Bq,Cq), z=1 -> (Bk,Ck). No transposes needed.
__global__ __launch_bounds__(256, 2) void gemm_qk_f32(
    const float* __restrict__ A, const float* __restrict__ Bq,
    const float* __restrict__ Bk, float* __restrict__ Cq, float* __restrict__ Ck,
    int Kdim, int Ndim) {
  const float* W = blockIdx.z ? Bk : Bq;
  float* C = blockIdx.z ? Ck : Cq;
  __shared__ float As[16][128];   // [k][row]
  __shared__ float Ws[16][128];   // [k][col]
  const int t = threadIdx.x, tx = t & 15, ty = t >> 4;
  const long bm = (long)blockIdx.y * 128, bn = (long)blockIdx.x * 128;
  float acc[8][8] = {};
  const int arow = t >> 1, akb = (t & 1) * 8;
  const float* aptr = A + (bm + arow) * (long)Kdim + akb;
  const float* wptr = W + (long)ty * Ndim + bn + tx * 8;

  for (int k0 = 0; k0 < Kdim; k0 += 16) {
    f32x4 av0 = *(const f32x4*)(aptr + k0);
    f32x4 av1 = *(const f32x4*)(aptr + k0 + 4);
    f32x4 wv0 = *(const f32x4*)(wptr + (long)k0 * Ndim);
    f32x4 wv1 = *(const f32x4*)(wptr + (long)k0 * Ndim + 4);
    __syncthreads();
#pragma unroll
    for (int u = 0; u < 4; ++u) {
      As[akb + u][arow] = av0[u];
      As[akb + 4 + u][arow] = av1[u];
    }
    *(f32x4*)&Ws[ty][tx * 8] = wv0;
    *(f32x4*)&Ws[ty][tx * 8 + 4] = wv1;
    __syncthreads();
#pragma unroll 4
    for (int kk = 0; kk < 16; ++kk) {
      f32x4 a0 = *(const f32x4*)&As[kk][ty * 8];
      f32x4 a1 = *(const f32x4*)&As[kk][ty * 8 + 4];
      f32x4 w0 = *(const f32x4*)&Ws[kk][tx * 8];
      f32x4 w1 = *(const f32x4*)&Ws[kk][tx * 8 + 4];
#pragma unroll
      for (int i = 0; i < 4; ++i)
#pragma unroll
        for (int j = 0; j < 4; ++j) {
          acc[i][j]         = fmaf(a0[i], w0[j], acc[i][j]);
          acc[i][j + 4]     = fmaf(a0[i], w1[j], acc[i][j + 4]);
          acc[i + 4][j]     = fmaf(a1[i], w0[j], acc[i + 4][j]);
          acc[i + 4][j + 4] = fmaf(a1[i], w1[j], acc[i + 4][j + 4]);
        }
    }
  }
#pragma unroll
  for (int i = 0; i < 8; ++i) {
    float* crow = C + (bm + ty * 8 + i) * (long)Ndim + bn + tx * 8;
    f32x4 o0 = {acc[i][0], acc[i][1], acc[i][2], acc[i][3]};
    f32x4 o1 = {acc[i][4], acc[i][5], acc[i][6], acc[i][7]};
    *(f32x4*)crow = o0;
    *(f32x4*)(crow + 4) = o1;
  }
}

// ---------------- Fully-VALU flash attention (no MFMA, no layout deps) ------
// S = (Q.K^T)*8 (quirk), online softmax, O = P@V.  Q,K f32; V,O bf16.
// grid (B*H=64, N/64=16), 256 threads: (tx = key/hd quad, ty = q quad).
__global__ __launch_bounds__(256, 2) void attn_f32(
    const float* __restrict__ Qf, const float* __restrict__ Kf,
    const u16* __restrict__ V, u16* __restrict__ O) {
  __shared__ float Qs[64][64];    // [hd][q]
  __shared__ float Ks[64][64];    // [hd][key]
  __shared__ u16   Vs[64][72];    // [key][hd] bf16, padded
  __shared__ float Ps[64][68];    // [key][q], padded
  const int b = blockIdx.x >> 4, h = blockIdx.x & 15;
  const int q0 = blockIdx.y * 64;
  const long base = (long)b * 1048576 + h * 64;
  const int t = threadIdx.x;
  const int tx = t & 15, ty = t >> 4;
  const int srow = t >> 2, sc16 = (t & 3) * 16;

  {  // stage Q transposed [hd][q] (once)
    const float* qsrc = Qf + base + (long)(q0 + srow) * 1024 + sc16;
#pragma unroll
    for (int u = 0; u < 16; ++u) Qs[sc16 + u][srow] = qsrc[u];
  }

  float mrow[4], lrow[4];
  float oacc[4][4] = {};
#pragma unroll
  for (int i = 0; i < 4; ++i) { mrow[i] = -1e30f; lrow[i] = 0.f; }

  for (int kt = 0; kt < 1024; kt += 64) {
    const float* ksrc = Kf + base + (long)(kt + srow) * 1024 + sc16;
    const u16* vsrc = V + base + (long)(kt + srow) * 1024 + sc16;
    float kreg[16];
#pragma unroll
    for (int u = 0; u < 16; ++u) kreg[u] = ksrc[u];
    bf16x8 vv0 = *(const bf16x8*)(vsrc);
    bf16x8 vv1 = *(const bf16x8*)(vsrc + 8);
    __syncthreads();  // (1) prior tile's LDS reads done
#pragma unroll
    for (int u = 0; u < 16; ++u) Ks[sc16 + u][srow] = kreg[u];
    *(bf16x8*)&Vs[srow][sc16] = vv0;
    *(bf16x8*)&Vs[srow][sc16 + 8] = vv1;
    __syncthreads();  // (2) K/V staged

    // ---- S = Q.K^T for this 64x64 tile: thread -> q=ty*4+i, key=tx*4+j ----
    float acc[4][4] = {};
#pragma unroll 8
    for (int kk = 0; kk < 64; ++kk) {
      f32x4 q4 = *(const f32x4*)&Qs[kk][ty * 4];
      f32x4 k4 = *(const f32x4*)&Ks[kk][tx * 4];
#pragma unroll
      for (int i = 0; i < 4; ++i)
#pragma unroll
        for (int j = 0; j < 4; ++j) acc[i][j] = fmaf(q4[i], k4[j], acc[i][j]);
    }

    // ---- online softmax (per-thread rows; 16-lane shfl over key groups) ----
#pragma unroll
    for (int i = 0; i < 4; ++i) {
      float p0 = acc[i][0] * 8.f, p1 = acc[i][1] * 8.f;   // quirk: * sqrt(64)
      float p2 = acc[i][2] * 8.f, p3 = acc[i][3] * 8.f;
      float pm = fmaxf(fmaxf(p0, p1), fmaxf(p2, p3));
#pragma unroll
      for (int off = 1; off < 16; off <<= 1) pm = fmaxf(pm, __shfl_xor(pm, off));
      const float mnew = fmaxf(mrow[i], pm);
      const float fsc = __expf(mrow[i] - mnew);
      p0 = __expf(p0 - mnew); p1 = __expf(p1 - mnew);
      p2 = __expf(p2 - mnew); p3 = __expf(p3 - mnew);
      float rs = p0 + p1 + p2 + p3;
#pragma unroll
      for (int off = 1; off < 16; off <<= 1) rs += __shfl_xor(rs, off);
      lrow[i] = lrow[i] * fsc + rs;
      mrow[i] = mnew;
#pragma unroll
      for (int j = 0; j < 4; ++j) oacc[i][j] *= fsc;
      Ps[tx * 4 + 0][ty * 4 + i] = p0;
      Ps[tx * 4 + 1][ty * 4 + i] = p1;
      Ps[tx * 4 + 2][ty * 4 + i] = p2;
      Ps[tx * 4 + 3][ty * 4 + i] = p3;
    }
    __syncthreads();  // (3) P visible

    // ---- O += P@V: thread -> q=ty*4+i, hd=tx*4+j --------------------------
#pragma unroll 4
    for (int key = 0; key < 64; ++key) {
      f32x4 p4 = *(const f32x4*)&Ps[key][ty * 4];
      ushort4 vu = *(const ushort4*)&Vs[key][tx * 4];
      const float v0 = bf2f(vu.x), v1 = bf2f(vu.y), v2 = bf2f(vu.z), v3 = bf2f(vu.w);
#pragma unroll
      for (int i = 0; i < 4; ++i) {
        oacc[i][0] = fmaf(p4[i], v0, oacc[i][0]);
        oacc[i][1] = fmaf(p4[i], v1, oacc[i][1]);
        oacc[i][2] = fmaf(p4[i], v2, oacc[i][2]);
        oacc[i][3] = fmaf(p4[i], v3, oacc[i][3]);
      }
    }
  }

#pragma unroll
  for (int i = 0; i < 4; ++i) {
    const float inv = 1.f / lrow[i];
    const long rowoff = ((long)b * 1024 + q0 + ty * 4 + i) * 1024 + h * 64 + tx * 4;
#pragma unroll
    for (int j = 0; j < 4; ++j) O[rowoff + j] = f2bf(oacc[i][j] * inv);
  }
}

// ---------------- LayerNorm over D=1024; bf16 in, bf16 or f32 out -----------
template <bool TWO, bool F32O>
__global__ __launch_bounds__(256) void ln_kernel(
    const u16* __restrict__ X, const u16* __restrict__ Y,
    const float* __restrict__ g, const float* __restrict__ be,
    void* __restrict__ outv) {
  const long row = blockIdx.x;
  const int t = threadIdx.x;
  const u16* xr = X + row * 1024 + t * 4;
  const u16* yr = Y + row * 1024 + t * 4;
  float v[4];
  float s1 = 0.f, s2 = 0.f;
#pragma unroll
  for (int i = 0; i < 4; ++i) {
    float x = bf2f(xr[i]);
    if (TWO) x += bf2f(yr[i]);
    v[i] = x; s1 += x; s2 += x * x;
  }
#pragma unroll
  for (int off = 1; off < 64; off <<= 1) {
    s1 += __shfl_xor(s1, off);
    s2 += __shfl_xor(s2, off);
  }
  __shared__ float red[8];
  const int wv = t >> 6;
  if ((t & 63) == 0) { red[wv * 2] = s1; red[wv * 2 + 1] = s2; }
  __syncthreads();
  s1 = red[0] + red[2] + red[4] + red[6];
  s2 = red[1] + red[3] + red[5] + red[7];
  const float mu = s1 * (1.f / 1024.f);
  const float var = s2 * (1.f / 1024.f) - mu * mu;
  const float rs = rsqrtf(var + 1e-5f);
#pragma unroll
  for (int i = 0; i < 4; ++i) {
    float o = (v[i] - mu) * rs * g[t * 4 + i] + be[t * 4 + i];
    if (F32O) ((float*)outv)[row * 1024 + t * 4 + i] = o;
    else ((u16*)outv)[row * 1024 + t * 4 + i] = f2bf(o);
  }
}

// ---- f32: qk32 = input+pos (f32), inbf = bf16(input) ------------------------
__global__ __launch_bounds__(256) void cvt_add(
    const float* __restrict__ a, const float* __restrict__ p,
    float* __restrict__ s32, u16* __restrict__ ab) {
  const int i = (blockIdx.x * 256 + threadIdx.x) * 4;
  float4 x = *(const float4*)(a + i);
  float4 y = *(const float4*)(p + i);
  float4 s = make_float4(x.x + y.x, x.y + y.y, x.z + y.z, x.w + y.w);
  *(float4*)(s32 + i) = s;
  ushort2* a2 = (ushort2*)(ab + i);
  a2[0] = make_ushort2(f2bf(x.x), f2bf(x.y));
  a2[1] = make_ushort2(f2bf(x.z), f2bf(x.w));
}

// ---- transpose f32 (rows x cols) -> bf16 (cols x rows) ----------------------
__global__ __launch_bounds__(256) void transpose_cvt(
    const float* __restrict__ src, u16* __restrict__ dst, int rows, int cols) {
  __shared__ u16 tile[32][33];
  const int tx = threadIdx.x & 31, ty = threadIdx.x >> 5;
  const long bx = (long)blockIdx.x * 32, by = (long)blockIdx.y * 32;
#pragma unroll
  for (int j = 0; j < 4; ++j)
    tile[ty + 8 * j][tx] = f2bf(src[(by + ty + 8 * j) * cols + bx + tx]);
  __syncthreads();
#pragma unroll
  for (int j = 0; j < 4; ++j)
    dst[(bx + ty + 8 * j) * rows + by + tx] = tile[tx][ty + 8 * j];
}

// ---- diagnostic sentinel: reveal ws_size via absmax channel ----------------
__global__ void sentinel_k(float* __restrict__ out, float v) {
  if (threadIdx.x == 0 && blockIdx.x == 0) out[0] = v;
}

extern "C" void kernel_launch(void* const* d_in, const int* in_sizes, int n_in,
                              void* d_out, int out_size, void* d_ws, size_t ws_size,
                              hipStream_t stream) {
  const float* input = (const float*)d_in[0];
  const float* pos   = (const float*)d_in[1];
  const float* Wq = (const float*)d_in[2];
  const float* Wk = (const float*)d_in[3];
  const float* Wv = (const float*)d_in[4];
  const float* W1 = (const float*)d_in[5];
  const float* b1 = (const float*)d_in[6];
  const float* W2 = (const float*)d_in[7];
  const float* b2 = (const float*)d_in[8];
  const float* g1  = (const float*)d_in[9];
  const float* be1 = (const float*)d_in[10];
  const float* g2  = (const float*)d_in[11];
  const float* be2 = (const float*)d_in[12];
  float* out = (float*)d_out;

  if (ws_size < (64ll << 20)) {
    sentinel_k<<<1, 64, 0, stream>>>(out, 2000.0f + (float)(ws_size >> 20));
    return;
  }

  // ws layout, 64 MiB peak (lifetimes in step numbers):
  //  [0,16)  qk32 f32 (1-2) -> Vb [0,8) (4-5) -> x1 [0,8) (6-8b)
  //  [8,16)                 -> at (5-6) -> W1T (7a-7b)
  //  [16,24) inbf (1-6)     -> W2T (8a-8b)
  //  [24,40) Qf f32 (2-5)   -> h1 [24,56) (7b-8b)
  //  [40,56) Kf f32 (2-5)   -> (h1)
  //  [56,58) WvT (3-4)      -> f2o [56,64) (8b-9)
  char* w = (char*)d_ws;
  float* qk32 = (float*)(w + (0ll  << 20));
  u16*   Vb   = (u16*)  (w + (0ll  << 20));
  u16*   x1   = (u16*)  (w + (0ll  << 20));
  u16*   at   = (u16*)  (w + (8ll  << 20));
  u16*   W1T  = (u16*)  (w + (8ll  << 20));
  u16*   inbf = (u16*)  (w + (16ll << 20));
  u16*   W2T  = (u16*)  (w + (16ll << 20));
  float* Qf   = (float*)(w + (24ll << 20));
  u16*   h1   = (u16*)  (w + (24ll << 20));
  float* Kf   = (float*)(w + (40ll << 20));
  u16*   WvT  = (u16*)  (w + (56ll << 20));
  u16*   f2o  = (u16*)  (w + (56ll << 20));

  /* 1 */ cvt_add<<<4096, 256, 0, stream>>>(input, pos, qk32, inbf);
  /* 2 */ gemm_qk_f32<<<dim3(8, 32, 2), 256, 0, stream>>>(qk32, Wq, Wk, Qf, Kf, 1024, 1024);
  /* 3 */ transpose_cvt<<<dim3(32, 32), 256, 0, stream>>>(Wv, WvT, 1024, 1024);
  /* 4 */ gemm_bt<0><<<dim3(8, 32), 256, 0, stream>>>(inbf, WvT, Vb, 4096, 1024, 1024, nullptr, nullptr);
  /* 5 */ attn_f32<<<dim3(64, 16), 256, 0, stream>>>(Qf, Kf, Vb, at);
  /* 6 */ ln_kernel<true, false><<<4096, 256, 0, stream>>>(inbf, at, g1, be1, (void*)x1);
  /* 7a*/ transpose_cvt<<<dim3(128, 32), 256, 0, stream>>>(W1, W1T, 1024, 4096);
  /* 7b*/ gemm_bt<1><<<dim3(32, 32), 256, 0, stream>>>(x1, W1T, h1, 4096, 4096, 1024, b1, nullptr);
  /* 8a*/ transpose_cvt<<<dim3(32, 128), 256, 0, stream>>>(W2, W2T, 4096, 1024);
  /* 8b*/ gemm_bt<2><<<dim3(8, 32), 256, 0, stream>>>(h1, W2T, f2o, 4096, 1024, 4096, b2, x1);
  /* 9 */ ln_kernel<false, true><<<4096, 256, 0, stream>>>(f2o, f2o, g2, be2, (void*)out);
}